// Round 8
// baseline (180.916 us; speedup 1.0000x reference)
//
#include <hip/hip_runtime.h>
#include <math.h>

#define Bc 2
#define Nc 2048
#define Ec 512
#define Hc 8
#define Dc 64
#define Mc 4096   // B*N
#define NT 32     // chunks per sequence
#define Cc 64     // chunk size

typedef short bf16x8 __attribute__((ext_vector_type(8)));
typedef float f32x4 __attribute__((ext_vector_type(4)));

// global -> LDS direct DMA, 16B per lane, dest = wave-uniform base + lane*16
#define GLOAD(g, l) __builtin_amdgcn_global_load_lds(                        \
    (const __attribute__((address_space(1))) unsigned*)(const void*)(g),     \
    (__attribute__((address_space(3))) unsigned*)(void*)(l), 16, 0, 0)

#define VMCNT(n) asm volatile("s_waitcnt vmcnt(" #n ")" ::: "memory")

__device__ __forceinline__ unsigned short f2bf(float x) {
    union { float f; unsigned u; } v; v.f = x;
    unsigned r = v.u + 0x7fffu + ((v.u >> 16) & 1u);   // RNE
    return (unsigned short)(r >> 16);
}
__device__ __forceinline__ float bf2f(unsigned short b) {
    union { float f; unsigned u; } v; v.u = ((unsigned)b) << 16;
    return v.f;
}

// gamma per head: 1 - exp(linspace(log(1/32), log(1/512), 8))
__device__ __forceinline__ float get_gamma(int h) {
    const float l0 = -3.4657359028f;
    const float l1 = -6.2383246250f;
    return 1.0f - expf(l0 + (l1 - l0) * ((float)h / 7.0f));
}

// ---------------------------------------------------------------------------
// split fp32 arrays into bf16 hi/lo pairs + xpos tables (transposed [32][2048]),
// one launch. IS tables have 1/sqrt(D)=0.125 folded in (K path).
struct SplitArgs {
    const float* src[8];
    unsigned short* hi[8];
    unsigned short* lo[8];
    int n[8];
};

__global__ __launch_bounds__(256) void prep_kernel(SplitArgs a,
                                                   float* __restrict__ sinS,
                                                   float* __restrict__ cosS,
                                                   float* __restrict__ sinIS,
                                                   float* __restrict__ cosIS) {
    int y = blockIdx.y;
    if (y == 8) {
        int idx = blockIdx.x * 256 + threadIdx.x;
        if (idx >= Nc * 32) return;
        int n = idx & 2047;
        int i = idx >> 11;                 // 0..31
        float xscale = (2.0f * (float)i + 25.6f) / 89.6f;
        float power  = ((float)n - 1024.0f) / 512.0f;
        float scale  = powf(xscale, power);
        float inv_freq = powf(10000.0f, -(float)i / 32.0f);
        float ang = (float)n * inv_freq;
        float s = sinf(ang), c = cosf(ang);
        int o = i * 2048 + n;              // transposed layout
        sinS[o]  = s * scale;
        cosS[o]  = c * scale;
        float rs = 0.125f / scale;         // fold K's 1/sqrt(D)
        sinIS[o] = s * rs;
        cosIS[o] = c * rs;
        return;
    }
    int i4 = (blockIdx.x * 256 + threadIdx.x) * 4;
    if (i4 >= a.n[y]) return;
    float4 v = *(const float4*)&a.src[y][i4];
    ushort4 h, l;
    h.x = f2bf(v.x); l.x = f2bf(v.x - bf2f(h.x));
    h.y = f2bf(v.y); l.y = f2bf(v.y - bf2f(h.y));
    h.z = f2bf(v.z); l.z = f2bf(v.z - bf2f(h.z));
    h.w = f2bf(v.w); l.w = f2bf(v.w - bf2f(h.w));
    *(ushort4*)&a.hi[y][i4] = h;
    *(ushort4*)&a.lo[y][i4] = l;
}

// ---------------------------------------------------------------------------
// shared epilogue: D[row][col]: col = lane&15, row = (lane>>4)*4 + reg
template<int TM, int TN, int WR, int WC, int MI, int NI>
__device__ __forceinline__ void gemm_epilogue(
    f32x4 (&acc)[MI][NI], int mode, int row0, int col0, int wr, int wc,
    int lrow, int quad, const float* bias,
    float* Qr, float* Kr, float* Vr, float* G, float* Out,
    const float* sinS, const float* cosS,
    const float* sinIS, const float* cosIS)
{
    if (mode <= 1) {
        const float* st = (mode == 0) ? sinS : sinIS;
        const float* ct = (mode == 0) ? cosS : cosIS;
        float* dst = (mode == 0) ? Qr : Kr;
        #pragma unroll
        for (int ni = 0; ni < NI; ++ni) {
            int c = col0 + wc * (TN / WC) + ni * 16 + lrow;
            int h = c >> 6, d = c & 63, pr = d >> 1;
            float bi = bias[c];
            #pragma unroll
            for (int mi = 0; mi < MI; ++mi) {
                int R0 = row0 + wr * (TM / WR) + mi * 16 + quad * 4;
                int bb = R0 >> 11;
                int n0 = R0 & 2047;
                float4 sv4 = *(const float4*)&st[pr * 2048 + n0];
                float4 cv4 = *(const float4*)&ct[pr * 2048 + n0];
                float svv[4] = {sv4.x, sv4.y, sv4.z, sv4.w};
                float cvv[4] = {cv4.x, cv4.y, cv4.z, cv4.w};
                #pragma unroll
                for (int reg = 0; reg < 4; ++reg) {
                    float x = acc[mi][ni][reg] + bi;
                    float p2 = __shfl_xor(x, 1, 64);       // partner column c^1
                    float y = (c & 1) ? fmaf(x, cvv[reg],  p2 * svv[reg])
                                      : fmaf(x, cvv[reg], -p2 * svv[reg]);
                    dst[(((size_t)(bb * Hc + h)) * Nc + n0 + reg) * Dc + d] = y;
                }
            }
        }
    } else if (mode == 2) {
        #pragma unroll
        for (int ni = 0; ni < NI; ++ni) {
            int c = col0 + wc * (TN / WC) + ni * 16 + lrow;
            int h = c >> 6, d = c & 63;
            float bi = bias[c];
            #pragma unroll
            for (int mi = 0; mi < MI; ++mi) {
                int R0 = row0 + wr * (TM / WR) + mi * 16 + quad * 4;
                int bb = R0 >> 11;
                int n0 = R0 & 2047;
                #pragma unroll
                for (int reg = 0; reg < 4; ++reg)
                    Vr[(((size_t)(bb * Hc + h)) * Nc + n0 + reg) * Dc + d] =
                        acc[mi][ni][reg] + bi;
            }
        }
    } else {
        #pragma unroll
        for (int ni = 0; ni < NI; ++ni) {
            int c = col0 + wc * (TN / WC) + ni * 16 + lrow;
            float bi = bias[c];
            #pragma unroll
            for (int mi = 0; mi < MI; ++mi) {
                int R0 = row0 + wr * (TM / WR) + mi * 16 + quad * 4;
                #pragma unroll
                for (int reg = 0; reg < 4; ++reg) {
                    float x = acc[mi][ni][reg] + bi;
                    if (mode == 3)
                        G[(size_t)(R0 + reg) * Ec + c] = x / (1.0f + expf(-x));
                    else
                        Out[(size_t)(R0 + reg) * Ec + c] = x;
                }
            }
        }
    }
}

// ---------------------------------------------------------------------------
// bf16x3 MFMA GEMM #1 (fused projections): 2-barrier double-buffered loop,
// counted VMCNT(8), 128x128 tile, 4 waves. Measured-best fused config (R4).
// x*w ~= xh*wh + xh*wl + xl*wh.
template<int TM, int TN, int WR, int WC>
__global__ __launch_bounds__(WR * WC * 64) void mgemm2_kernel(
    const unsigned short* __restrict__ Xq_h, const unsigned short* __restrict__ Xq_l,
    const unsigned short* __restrict__ Xk_h, const unsigned short* __restrict__ Xk_l,
    const unsigned short* __restrict__ Xv_h, const unsigned short* __restrict__ Xv_l,
    const unsigned short* __restrict__ Wq_h, const unsigned short* __restrict__ Wq_l,
    const unsigned short* __restrict__ Wk_h, const unsigned short* __restrict__ Wk_l,
    const unsigned short* __restrict__ Wv_h, const unsigned short* __restrict__ Wv_l,
    const unsigned short* __restrict__ Wg_h, const unsigned short* __restrict__ Wg_l,
    const float* __restrict__ bq, const float* __restrict__ bk, const float* __restrict__ bv,
    const float* __restrict__ bg,
    float* __restrict__ Qr, float* __restrict__ Kr, float* __restrict__ Vr,
    float* __restrict__ G,
    const float* __restrict__ sinS, const float* __restrict__ cosS,
    const float* __restrict__ sinIS, const float* __restrict__ cosIS)
{
    constexpr int THREADS = WR * WC * 64;
    constexpr int MI  = TM / WR / 16;
    constexpr int NI  = TN / WC / 16;
    constexpr int RA  = TM * 4 / THREADS;
    constexpr int RB  = TN * 4 / THREADS;
    constexpr int GL  = 2 * (RA + RB);
    constexpr int BUF = (TM + TN) * 64;
    constexpr int ALo = TM * 32;
    constexpr int BHo = TM * 64;
    constexpr int BLo = TM * 64 + TN * 32;
    static_assert(GL == 8, "vmcnt literal");

    // XCD-chunked bijective swizzle (nwg % 8 == 0)
    int gx = gridDim.x, gy = gridDim.y;
    int nwg = gx * gy * gridDim.z;
    int id = blockIdx.x + gx * (blockIdx.y + gy * blockIdx.z);
    int sid = (id & 7) * (nwg >> 3) + (id >> 3);
    int bx = sid % gx; int rest = sid / gx;
    int by = rest % gy; int bz = rest / gy;

    int mode = bz;
    const unsigned short *Xh, *Xl, *Wh, *Wl; const float* bias;
    switch (mode) {
        case 0:  Xh = Xq_h; Xl = Xq_l; Wh = Wq_h; Wl = Wq_l; bias = bq; break;
        case 1:  Xh = Xk_h; Xl = Xk_l; Wh = Wk_h; Wl = Wk_l; bias = bk; break;
        case 2:  Xh = Xv_h; Xl = Xv_l; Wh = Wv_h; Wl = Wv_l; bias = bv; break;
        default: Xh = Xq_h; Xl = Xq_l; Wh = Wg_h; Wl = Wg_l; bias = bg; break;
    }

    __shared__ __align__(16) short lds[2 * BUF];

    int tid  = threadIdx.x;
    int lane = tid & 63;
    int w    = tid >> 6;
    int wr   = w / WC, wc = w % WC;
    int row0 = bx * TM, col0 = by * TN;
    int lrow = lane & 15, lslot = lane >> 4;

    f32x4 acc[MI][NI];
    #pragma unroll
    for (int i = 0; i < MI; ++i)
        #pragma unroll
        for (int j = 0; j < NI; ++j) acc[i][j] = {0.f, 0.f, 0.f, 0.f};

    int aoff[MI], boff[NI];
    #pragma unroll
    for (int mi = 0; mi < MI; ++mi) {
        int r = wr * (TM / WR) + mi * 16 + lrow;
        aoff[mi] = (r * 4 + (lslot ^ ((r >> 1) & 3))) * 8;
    }
    #pragma unroll
    for (int ni = 0; ni < NI; ++ni) {
        int r = wc * (TN / WC) + ni * 16 + lrow;
        boff[ni] = (r * 4 + (lslot ^ ((r >> 1) & 3))) * 8;
    }

    auto stage = [&](int buf, int k0) {
        short* l = &lds[buf * BUF];
        #pragma unroll
        for (int i = 0; i < RA; ++i) {
            int q = i * THREADS + tid;
            int r = q >> 2;
            int sp = (q & 3) ^ ((r >> 1) & 3);
            int base = (i * THREADS + (w << 6)) * 8;
            size_t ga = (size_t)(row0 + r) * Ec + k0 + sp * 8;
            GLOAD(Xh + ga, &l[base]);
            GLOAD(Xl + ga, &l[ALo + base]);
        }
        #pragma unroll
        for (int i = 0; i < RB; ++i) {
            int q = i * THREADS + tid;
            int r = q >> 2;
            int sp = (q & 3) ^ ((r >> 1) & 3);
            int base = (i * THREADS + (w << 6)) * 8;
            size_t gb = (size_t)(col0 + r) * Ec + k0 + sp * 8;
            GLOAD(Wh + gb, &l[BHo + base]);
            GLOAD(Wl + gb, &l[BLo + base]);
        }
    };

    stage(0, 0);
    for (int t = 0; t < Ec / 32; ++t) {
        int cur = t & 1;
        if (t < Ec / 32 - 1) {
            stage(cur ^ 1, (t + 1) * 32);
            VMCNT(8);        // wait tile-t loads; prefetch stays in flight
        } else {
            VMCNT(0);
        }
        __builtin_amdgcn_s_barrier();
        __builtin_amdgcn_sched_barrier(0);

        const short* l = &lds[cur * BUF];
        bf16x8 ah[MI], al[MI], bh[NI], bl[NI];
        #pragma unroll
        for (int mi = 0; mi < MI; ++mi) {
            ah[mi] = *(const bf16x8*)&l[aoff[mi]];
            al[mi] = *(const bf16x8*)&l[ALo + aoff[mi]];
        }
        #pragma unroll
        for (int ni = 0; ni < NI; ++ni) {
            bh[ni] = *(const bf16x8*)&l[BHo + boff[ni]];
            bl[ni] = *(const bf16x8*)&l[BLo + boff[ni]];
        }
        #pragma unroll
        for (int mi = 0; mi < MI; ++mi)
            #pragma unroll
            for (int ni = 0; ni < NI; ++ni) {
                acc[mi][ni] = __builtin_amdgcn_mfma_f32_16x16x32_bf16(ah[mi], bh[ni], acc[mi][ni], 0, 0, 0);
                acc[mi][ni] = __builtin_amdgcn_mfma_f32_16x16x32_bf16(ah[mi], bl[ni], acc[mi][ni], 0, 0, 0);
                acc[mi][ni] = __builtin_amdgcn_mfma_f32_16x16x32_bf16(al[mi], bh[ni], acc[mi][ni], 0, 0, 0);
            }
        asm volatile("s_waitcnt lgkmcnt(0)" ::: "memory");
        __builtin_amdgcn_sched_barrier(0);
        __builtin_amdgcn_s_barrier();
    }

    gemm_epilogue<TM, TN, WR, WC, MI, NI>(acc, mode, row0, col0, wr, wc,
        lrow, lslot, bias, Qr, Kr, Vr, G, (float*)nullptr,
        sinS, cosS, sinIS, cosIS);
}

// ---------------------------------------------------------------------------
// bf16x3 MFMA GEMM #2 (final projection): 4-phase interleaved schedule,
// tri-buffered LDS, staging 2 ahead, counted VMCNT(6). Measured-best final (R7).
template<int TM, int TN, int WR, int WC>
__global__ __launch_bounds__(WR * WC * 64) void mgemm4_kernel(
    const unsigned short* __restrict__ Xr_h, const unsigned short* __restrict__ Xr_l,
    const unsigned short* __restrict__ Wo_h, const unsigned short* __restrict__ Wo_l,
    const float* __restrict__ bo, float* __restrict__ Out)
{
    constexpr int THREADS = WR * WC * 64;
    constexpr int MI  = TM / WR / 16;
    constexpr int NI  = TN / WC / 16;
    constexpr int RA  = TM * 4 / THREADS;
    constexpr int RB  = TN * 4 / THREADS;
    constexpr int BUF = (TM + TN) * 64;
    constexpr int ALo = TM * 32;
    constexpr int BHo = TM * 64;
    constexpr int BLo = TM * 64 + TN * 32;
    constexpr int NSTEP = Ec / 32;
    static_assert(RA == 1 && RB == 2 && NI == 4, "phase schedule assumes this shape");

    // XCD-chunked bijective swizzle
    int gx = gridDim.x;
    int nwg = gx * gridDim.y;
    int id = blockIdx.x + gx * blockIdx.y;
    int sid = (id & 7) * (nwg >> 3) + (id >> 3);
    int bx = sid % gx; int by = sid / gx;

    __shared__ __align__(16) short lds[3 * BUF];

    int tid  = threadIdx.x;
    int lane = tid & 63;
    int w    = tid >> 6;
    int wr   = w / WC, wc = w % WC;
    int row0 = bx * TM, col0 = by * TN;
    int lrow = lane & 15, lslot = lane >> 4;

    f32x4 acc[MI][NI];
    #pragma unroll
    for (int i = 0; i < MI; ++i)
        #pragma unroll
        for (int j = 0; j < NI; ++j) acc[i][j] = {0.f, 0.f, 0.f, 0.f};

    int aoff[MI], boff[NI];
    #pragma unroll
    for (int mi = 0; mi < MI; ++mi) {
        int r = wr * (TM / WR) + mi * 16 + lrow;
        aoff[mi] = (r * 4 + (lslot ^ ((r >> 1) & 3))) * 8;
    }
    #pragma unroll
    for (int ni = 0; ni < NI; ++ni) {
        int r = wc * (TN / WC) + ni * 16 + lrow;
        boff[ni] = (r * 4 + (lslot ^ ((r >> 1) & 3))) * 8;
    }

    auto stage_full = [&](int buf, int k0) {
        short* l = &lds[buf * BUF];
        {
            int q = tid;
            int r = q >> 2;
            int sp = (q & 3) ^ ((r >> 1) & 3);
            int base = (w << 6) * 8;
            size_t ga = (size_t)(row0 + r) * Ec + k0 + sp * 8;
            GLOAD(Xr_h + ga, &l[base]);
            GLOAD(Xr_l + ga, &l[ALo + base]);
        }
        #pragma unroll
        for (int i = 0; i < RB; ++i) {
            int q = i * THREADS + tid;
            int r = q >> 2;
            int sp = (q & 3) ^ ((r >> 1) & 3);
            int base = (i * THREADS + (w << 6)) * 8;
            size_t gb = (size_t)(col0 + r) * Ec + k0 + sp * 8;
            GLOAD(Wo_h + gb, &l[BHo + base]);
            GLOAD(Wo_l + gb, &l[BLo + base]);
        }
    };
    auto stage_portion = [&](int buf, int k0, int p) {
        short* l = &lds[buf * BUF];
        if (p == 0) {
            int q = tid;
            int r = q >> 2;
            int sp = (q & 3) ^ ((r >> 1) & 3);
            int base = (w << 6) * 8;
            size_t ga = (size_t)(row0 + r) * Ec + k0 + sp * 8;
            GLOAD(Xr_h + ga, &l[base]);
            GLOAD(Xr_l + ga, &l[ALo + base]);
        } else if (p <= 2) {
            int i = p - 1;
            int q = i * THREADS + tid;
            int r = q >> 2;
            int sp = (q & 3) ^ ((r >> 1) & 3);
            int base = (i * THREADS + (w << 6)) * 8;
            size_t gb = (size_t)(col0 + r) * Ec + k0 + sp * 8;
            GLOAD(Wo_h + gb, &l[BHo + base]);
            GLOAD(Wo_l + gb, &l[BLo + base]);
        }
    };

    stage_full(0, 0);
    stage_full(1, 32);
    VMCNT(6);
    __builtin_amdgcn_s_barrier();

    bf16x8 ah[MI], al[MI];
    for (int t = 0; t < NSTEP; ++t) {
        const int cur = t % 3;
        const short* l = &lds[cur * BUF];
        const bool pre = (t + 2) < NSTEP;
        const int nb = (t + 2) % 3;
        const int nk = (t + 2) * 32;
        #pragma unroll
        for (int p = 0; p < 4; ++p) {
            if (p == 0) {
                #pragma unroll
                for (int mi = 0; mi < MI; ++mi) {
                    ah[mi] = *(const bf16x8*)&l[aoff[mi]];
                    al[mi] = *(const bf16x8*)&l[ALo + aoff[mi]];
                }
            }
            bf16x8 bh2 = *(const bf16x8*)&l[BHo + boff[p]];
            bf16x8 bl2 = *(const bf16x8*)&l[BLo + boff[p]];
            if (pre) stage_portion(nb, nk, p);
            __builtin_amdgcn_s_barrier();
            asm volatile("s_waitcnt lgkmcnt(0)" ::: "memory");
            __builtin_amdgcn_sched_barrier(0);
            __builtin_amdgcn_s_setprio(1);
            #pragma unroll
            for (int mi = 0; mi < MI; ++mi) {
                acc[mi][p] = __builtin_amdgcn_mfma_f32_16x16x32_bf16(ah[mi], bh2, acc[mi][p], 0, 0, 0);
                acc[mi][p] = __builtin_amdgcn_mfma_f32_16x16x32_bf16(ah[mi], bl2, acc[mi][p], 0, 0, 0);
                acc[mi][p] = __builtin_amdgcn_mfma_f32_16x16x32_bf16(al[mi], bh2, acc[mi][p], 0, 0, 0);
            }
            __builtin_amdgcn_s_setprio(0);
            if (p == 3) { if (pre) VMCNT(6); else VMCNT(0); }
            __builtin_amdgcn_s_barrier();
        }
    }

    // epilogue (mode 4 only): Out = acc + bias
    int quad = lslot;
    #pragma unroll
    for (int ni = 0; ni < NI; ++ni) {
        int c = col0 + wc * (TN / WC) + ni * 16 + lrow;
        float bi = bo[c];
        #pragma unroll
        for (int mi = 0; mi < MI; ++mi) {
            int R0 = row0 + wr * (TM / WR) + mi * 16 + quad * 4;
            #pragma unroll
            for (int reg = 0; reg < 4; ++reg)
                Out[(size_t)(R0 + reg) * Ec + c] = acc[mi][ni][reg] + bi;
        }
    }
}

// ---------------------------------------------------------------------------
// Phase A: per (bh, chunk) local state  L[dk][dv] = sum_s gamma^(64-s) K[s][dk] V[s][dv]
__global__ __launch_bounds__(256) void phaseA_kernel(const float* __restrict__ Kr,
                                                     const float* __restrict__ Vr,
                                                     float* __restrict__ L)
{
    int bh = blockIdx.x;
    int t  = blockIdx.y;
    float gamma = get_gamma(bh & 7);
    float lg = logf(gamma);

    __shared__ float Ks[64][68];
    __shared__ float Vs[64][68];

    int tid = threadIdx.x;
    const float* Kc = Kr + (size_t)(bh * Nc + t * Cc) * Dc;
    const float* Vc = Vr + (size_t)(bh * Nc + t * Cc) * Dc;

    #pragma unroll
    for (int i = 0; i < 4; ++i) {
        int f = tid + i * 256;
        int s = f >> 4;
        int d = (f & 15) << 2;
        float w = expf(lg * (float)(Cc - s));
        float4 kv = *(const float4*)&Kc[s * Dc + d];
        float4 ks = {kv.x * w, kv.y * w, kv.z * w, kv.w * w};
        *(float4*)&Ks[s][d] = ks;
        float4 vv = *(const float4*)&Vc[s * Dc + d];
        *(float4*)&Vs[s][d] = vv;
    }
    __syncthreads();

    int tx = tid & 15, ty = tid >> 4;
    float acc[4][4];
    #pragma unroll
    for (int i = 0; i < 4; ++i)
        #pragma unroll
        for (int j = 0; j < 4; ++j) acc[i][j] = 0.0f;

    for (int s = 0; s < 64; ++s) {
        float4 a = *(const float4*)&Ks[s][ty * 4];
        float4 b = *(const float4*)&Vs[s][tx * 4];
        float av[4] = {a.x, a.y, a.z, a.w};
        float bv[4] = {b.x, b.y, b.z, b.w};
        #pragma unroll
        for (int i = 0; i < 4; ++i)
            #pragma unroll
            for (int j = 0; j < 4; ++j)
                acc[i][j] = fmaf(av[i], bv[j], acc[i][j]);
    }

    float* Lp = L + (size_t)(bh * NT + t) * 4096;
    #pragma unroll
    for (int i = 0; i < 4; ++i) {
        float4 o = {acc[i][0], acc[i][1], acc[i][2], acc[i][3]};
        *(float4*)&Lp[(ty * 4 + i) * 64 + tx * 4] = o;
    }
}

// ---------------------------------------------------------------------------
// Phase B: S_0 = 0 ; S_{t+1} = gamma^64 * S_t + L_t  (S_t written pre-fold)
// grid (16, 16), 64-thread blocks: each block owns one 256-float slice.
__global__ __launch_bounds__(64) void scan_kernel(const float* __restrict__ L,
                                                  float* __restrict__ Sst)
{
    int bh = blockIdx.x;
    int part = blockIdx.y;
    int tid = threadIdx.x;
    float gamma = get_gamma(bh & 7);
    float g64 = expf(logf(gamma) * 64.0f);

    float4 s = {0.0f, 0.0f, 0.0f, 0.0f};
    size_t base = (size_t)bh * NT * 4096 + part * 256 + tid * 4;
    const float* Lp = L + base;
    float* Sp = Sst + base;
    for (int t = 0; t < NT; ++t) {
        *(float4*)&Sp[(size_t)t * 4096] = s;
        float4 l = *(const float4*)&Lp[(size_t)t * 4096];
        s.x = s.x * g64 + l.x;
        s.y = s.y * g64 + l.y;
        s.z = s.z * g64 + l.z;
        s.w = s.w * g64 + l.w;
    }
}

// ---------------------------------------------------------------------------
// Phase C: O = tril-decayed(QK^T) @ V + gamma^i * Q @ S, LayerNorm, gate,
// write retG as bf16 hi/lo in (B,N,E) layout.
__global__ __launch_bounds__(256) void phaseC_kernel(
    const float* __restrict__ Qr, const float* __restrict__ Kr, const float* __restrict__ Vr,
    const float* __restrict__ Sst, const float* __restrict__ G,
    unsigned short* __restrict__ retGh, unsigned short* __restrict__ retGl)
{
    int bh = blockIdx.x, t = blockIdx.y;
    int b = bh >> 3, h = bh & 7;
    float gamma = get_gamma(h);
    float lg = logf(gamma);

    __shared__ float QsT[64][68];
    __shared__ float KsT[64][68];
    __shared__ float Ss[64][68];

    int tid = threadIdx.x;
    const float* Qc = Qr + (size_t)(bh * Nc + t * Cc) * Dc;
    const float* Kc = Kr + (size_t)(bh * Nc + t * Cc) * Dc;
    const float* Sp = Sst + (size_t)(bh * NT + t) * 4096;

    #pragma unroll
    for (int i = 0; i < 4; ++i) {
        int f = tid + i * 256;
        int r = f >> 4;
        int d = (f & 15) << 2;
        float wq = expf(lg * (float)r);
        float4 q = *(const float4*)&Qc[r * Dc + d];
        QsT[d + 0][r] = q.x * wq; QsT[d + 1][r] = q.y * wq;
        QsT[d + 2][r] = q.z * wq; QsT[d + 3][r] = q.w * wq;
        float wk = expf(-lg * (float)r);
        float4 kk = *(const float4*)&Kc[r * Dc + d];
        KsT[d + 0][r] = kk.x * wk; KsT[d + 1][r] = kk.y * wk;
        KsT[d + 2][r] = kk.z * wk; KsT[d + 3][r] = kk.w * wk;
        float4 sv = *(const float4*)&Sp[r * 64 + d];
        *(float4*)&Ss[r][d] = sv;
    }
    __syncthreads();

    int tx = tid & 15, ty = tid >> 4;
    float accA[4][4], accO[4][4];
    #pragma unroll
    for (int i = 0; i < 4; ++i)
        #pragma unroll
        for (int j = 0; j < 4; ++j) { accA[i][j] = 0.0f; accO[i][j] = 0.0f; }

    for (int d = 0; d < 64; ++d) {
        float4 a  = *(const float4*)&QsT[d][ty * 4];
        float4 kb = *(const float4*)&KsT[d][tx * 4];
        float4 sb = *(const float4*)&Ss[d][tx * 4];
        float av[4] = {a.x, a.y, a.z, a.w};
        float kv[4] = {kb.x, kb.y, kb.z, kb.w};
        float sv[4] = {sb.x, sb.y, sb.z, sb.w};
        #pragma unroll
        for (int i = 0; i < 4; ++i)
            #pragma unroll
            for (int j = 0; j < 4; ++j) {
                accA[i][j] = fmaf(av[i], kv[j], accA[i][j]);
                accO[i][j] = fmaf(av[i], sv[j], accO[i][j]);
            }
    }
    __syncthreads();

    #pragma unroll
    for (int i = 0; i < 4; ++i) {
        int gi = ty * 4 + i;
        #pragma unroll
        for (int j = 0; j < 4; ++j) {
            int gj = tx * 4 + j;
            KsT[gj][gi] = (gj <= gi) ? accA[i][j] : 0.0f;
        }
    }
    const float* Vc = Vr + (size_t)(bh * Nc + t * Cc) * Dc;
    #pragma unroll
    for (int i = 0; i < 4; ++i) {
        int f = tid + i * 256;
        int r = f >> 4;
        int d = (f & 15) << 2;
        float4 vv = *(const float4*)&Vc[r * Dc + d];
        *(float4*)&QsT[r][d] = vv;
    }
    __syncthreads();

    for (int j = 0; j < 64; ++j) {
        float4 a = *(const float4*)&KsT[j][ty * 4];
        float4 v = *(const float4*)&QsT[j][tx * 4];
        float av[4] = {a.x, a.y, a.z, a.w};
        float vv[4] = {v.x, v.y, v.z, v.w};
        #pragma unroll
        for (int i = 0; i < 4; ++i)
            #pragma unroll
            for (int jj = 0; jj < 4; ++jj)
                accO[i][jj] = fmaf(av[i], vv[jj], accO[i][jj]);
    }

    // LayerNorm over D=64 per row (row spread across 16 tx lanes)
    #pragma unroll
    for (int i = 0; i < 4; ++i) {
        float sum = accO[i][0] + accO[i][1] + accO[i][2] + accO[i][3];
        float sq  = accO[i][0] * accO[i][0] + accO[i][1] * accO[i][1]
                  + accO[i][2] * accO[i][2] + accO[i][3] * accO[i][3];
        #pragma unroll
        for (int m = 1; m < 16; m <<= 1) {
            sum += __shfl_xor(sum, m, 64);
            sq  += __shfl_xor(sq,  m, 64);
        }
        float mean = sum * (1.0f / 64.0f);
        float var  = sq * (1.0f / 64.0f) - mean * mean;
        float rinv = rsqrtf(var + 1e-6f);
        #pragma unroll
        for (int jj = 0; jj < 4; ++jj)
            accO[i][jj] = (accO[i][jj] - mean) * rinv;
    }

    // gate multiply + hi/lo bf16 store to (B, N, E)
    #pragma unroll
    for (int i = 0; i < 4; ++i) {
        int n = t * Cc + ty * 4 + i;
        size_t idx = ((size_t)b * Nc + n) * Ec + h * Dc + tx * 4;
        float4 g = *(const float4*)&G[idx];
        float o0 = accO[i][0] * g.x, o1 = accO[i][1] * g.y;
        float o2 = accO[i][2] * g.z, o3 = accO[i][3] * g.w;
        ushort4 hh, ll;
        hh.x = f2bf(o0); ll.x = f2bf(o0 - bf2f(hh.x));
        hh.y = f2bf(o1); ll.y = f2bf(o1 - bf2f(hh.y));
        hh.z = f2bf(o2); ll.z = f2bf(o2 - bf2f(hh.z));
        hh.w = f2bf(o3); ll.w = f2bf(o3 - bf2f(hh.w));
        *(ushort4*)&retGh[idx] = hh;
        *(ushort4*)&retGl[idx] = ll;
    }
}

// ---------------------------------------------------------------------------
extern "C" void kernel_launch(void* const* d_in, const int* in_sizes, int n_in,
                              void* d_out, int out_size, void* d_ws, size_t ws_size,
                              hipStream_t stream) {
    const float* query = (const float*)d_in[0];
    const float* key   = (const float*)d_in[1];
    const float* value = (const float*)d_in[2];
    const float* Wq = (const float*)d_in[3];
    const float* bq = (const float*)d_in[4];
    const float* Wk = (const float*)d_in[5];
    const float* bk = (const float*)d_in[6];
    const float* Wv = (const float*)d_in[7];
    const float* bv = (const float*)d_in[8];
    const float* Wg = (const float*)d_in[9];
    const float* bg = (const float*)d_in[10];
    const float* Wo = (const float*)d_in[11];
    const float* bo = (const float*)d_in[12];
    float* out = (float*)d_out;

    float* wsf = (float*)d_ws;
    const size_t SZ = (size_t)Bc * Nc * Ec;   // 2,097,152

    float* Qr = wsf;                 // fp32 (B,H,N,D)
    float* Kr = Qr + SZ;
    float* Vr = Kr + SZ;
    float* G  = Vr + SZ;             // fp32 (B,N,E)

    // X hi/lo region [4SZ, 7SZ) floats — dead after fused GEMM, then reused:
    unsigned short* Xq_h = (unsigned short*)(wsf + 4 * SZ);
    unsigned short* Xq_l = Xq_h + SZ;
    unsigned short* Xk_h = Xq_l + SZ;
    unsigned short* Xk_l = Xk_h + SZ;
    unsigned short* Xv_h = Xk_l + SZ;
    unsigned short* Xv_l = Xv_h + SZ;
    float* L   = wsf + 4 * SZ;                       // overlays Xq (after GEMM)
    float* Sst = wsf + 5 * SZ;                       // overlays Xk
    unsigned short* retGh = (unsigned short*)(wsf + 6 * SZ);  // overlays Xv
    unsigned short* retGl = retGh + SZ;

    const size_t WSZ = (size_t)Ec * Ec;      // 262,144
    unsigned short* Wp = (unsigned short*)(wsf + 7 * SZ);
    unsigned short* Wq_h = Wp;            unsigned short* Wq_l = Wp + WSZ;
    unsigned short* Wk_h = Wp + 2 * WSZ;  unsigned short* Wk_l = Wp + 3 * WSZ;
    unsigned short* Wv_h = Wp + 4 * WSZ;  unsigned short* Wv_l = Wp + 5 * WSZ;
    unsigned short* Wg_h = Wp + 6 * WSZ;  unsigned short* Wg_l = Wp + 7 * WSZ;
    unsigned short* Wo_h = Wp + 8 * WSZ;  unsigned short* Wo_l = Wp + 9 * WSZ;

    float* tab = wsf + 7 * SZ + (10 * WSZ) / 2;
    float* sinS  = tab;
    float* cosS  = sinS + Nc * 32;
    float* sinIS = cosS + Nc * 32;
    float* cosIS = sinIS + Nc * 32;

    SplitArgs sa;
    sa.src[0] = query; sa.hi[0] = Xq_h; sa.lo[0] = Xq_l; sa.n[0] = (int)SZ;
    sa.src[1] = key;   sa.hi[1] = Xk_h; sa.lo[1] = Xk_l; sa.n[1] = (int)SZ;
    sa.src[2] = value; sa.hi[2] = Xv_h; sa.lo[2] = Xv_l; sa.n[2] = (int)SZ;
    sa.src[3] = Wq;    sa.hi[3] = Wq_h; sa.lo[3] = Wq_l; sa.n[3] = (int)WSZ;
    sa.src[4] = Wk;    sa.hi[4] = Wk_h; sa.lo[4] = Wk_l; sa.n[4] = (int)WSZ;
    sa.src[5] = Wv;    sa.hi[5] = Wv_h; sa.lo[5] = Wv_l; sa.n[5] = (int)WSZ;
    sa.src[6] = Wg;    sa.hi[6] = Wg_h; sa.lo[6] = Wg_l; sa.n[6] = (int)WSZ;
    sa.src[7] = Wo;    sa.hi[7] = Wo_h; sa.lo[7] = Wo_l; sa.n[7] = (int)WSZ;
    prep_kernel<<<dim3(2048, 9), dim3(256), 0, stream>>>(sa, sinS, cosS, sinIS, cosIS);

    // fused Q/K/V/G projections: 128x128, 2-barrier dbuf (measured-best, R4)
    mgemm2_kernel<128, 128, 2, 2><<<dim3(Mc / 128, Ec / 128, 4), dim3(256), 0, stream>>>(
        Xq_h, Xq_l, Xk_h, Xk_l, Xv_h, Xv_l,
        Wq_h, Wq_l, Wk_h, Wk_l, Wv_h, Wv_l, Wg_h, Wg_l,
        bq, bk, bv, bg, Qr, Kr, Vr, G,
        sinS, cosS, sinIS, cosIS);

    phaseA_kernel<<<dim3(Bc * Hc, NT), dim3(256), 0, stream>>>(Kr, Vr, L);
    scan_kernel<<<dim3(Bc * Hc, 16), dim3(64), 0, stream>>>(L, Sst);
    phaseC_kernel<<<dim3(Bc * Hc, NT), dim3(256), 0, stream>>>(Qr, Kr, Vr, Sst, G, retGh, retGl);

    // final: out = retG @ Wo^T + bo, 64x128 4-phase (measured-best, R7)
    mgemm4_kernel<64, 128, 2, 2><<<dim3(Mc / 64, Ec / 128), dim3(256), 0, stream>>>(
        retGh, retGl, Wo_h, Wo_l, bo, out);
}

// Round 10
// 159.788 us; speedup vs baseline: 1.1322x; 1.1322x over previous
//
#include <hip/hip_runtime.h>
#include <math.h>

#define Bc 2
#define Nc 2048
#define Ec 512
#define Hc 8
#define Dc 64
#define Mc 4096   // B*N
#define NT 32     // chunks per sequence
#define Cc 64     // chunk size

typedef _Float16 f16x8 __attribute__((ext_vector_type(8)));
typedef float f32x4 __attribute__((ext_vector_type(4)));

// global -> LDS direct DMA, 16B per lane, dest = wave-uniform base + lane*16
#define GLOAD(g, l) __builtin_amdgcn_global_load_lds(                        \
    (const __attribute__((address_space(1))) unsigned*)(const void*)(g),     \
    (__attribute__((address_space(3))) unsigned*)(void*)(l), 16, 0, 0)

#define VMCNT(n) asm volatile("s_waitcnt vmcnt(" #n ")" ::: "memory")

union H4 { _Float16 h[4]; ushort4 u; };

// gamma per head: 1 - exp(linspace(log(1/32), log(1/512), 8))
__device__ __forceinline__ float get_gamma(int h) {
    const float l0 = -3.4657359028f;
    const float l1 = -6.2383246250f;
    return 1.0f - expf(l0 + (l1 - l0) * ((float)h / 7.0f));
}

// ---------------------------------------------------------------------------
// convert fp32 arrays to fp16 + xpos tables (transposed [32][2048]), one launch.
// IS tables have 1/sqrt(D)=0.125 folded in (K path).
struct SplitArgs {
    const float* src[8];
    unsigned short* dst[8];
    int n[8];
};

__global__ __launch_bounds__(256) void prep_kernel(SplitArgs a,
                                                   float* __restrict__ sinS,
                                                   float* __restrict__ cosS,
                                                   float* __restrict__ sinIS,
                                                   float* __restrict__ cosIS) {
    int y = blockIdx.y;
    if (y == 8) {
        int idx = blockIdx.x * 256 + threadIdx.x;
        if (idx >= Nc * 32) return;
        int n = idx & 2047;
        int i = idx >> 11;                 // 0..31
        float xscale = (2.0f * (float)i + 25.6f) / 89.6f;
        float power  = ((float)n - 1024.0f) / 512.0f;
        float scale  = powf(xscale, power);
        float inv_freq = powf(10000.0f, -(float)i / 32.0f);
        float ang = (float)n * inv_freq;
        float s = sinf(ang), c = cosf(ang);
        int o = i * 2048 + n;              // transposed layout
        sinS[o]  = s * scale;
        cosS[o]  = c * scale;
        float rs = 0.125f / scale;         // fold K's 1/sqrt(D)
        sinIS[o] = s * rs;
        cosIS[o] = c * rs;
        return;
    }
    int i4 = (blockIdx.x * 256 + threadIdx.x) * 4;
    if (i4 >= a.n[y]) return;
    float4 v = *(const float4*)&a.src[y][i4];
    H4 o;
    o.h[0] = (_Float16)v.x; o.h[1] = (_Float16)v.y;
    o.h[2] = (_Float16)v.z; o.h[3] = (_Float16)v.w;
    *(ushort4*)&a.dst[y][i4] = o.u;
}

// ---------------------------------------------------------------------------
// shared epilogue: D[row][col]: col = lane&15, row = (lane>>4)*4 + reg
template<int TM, int TN, int WR, int WC, int MI, int NI>
__device__ __forceinline__ void gemm_epilogue(
    f32x4 (&acc)[MI][NI], int mode, int row0, int col0, int wr, int wc,
    int lrow, int quad, const float* bias,
    float* Qr, float* Kr, float* Vr, float* G, float* Out,
    unsigned short* retG,
    const float* sinS, const float* cosS,
    const float* sinIS, const float* cosIS)
{
    if (mode <= 1) {
        const float* st = (mode == 0) ? sinS : sinIS;
        const float* ct = (mode == 0) ? cosS : cosIS;
        float* dst = (mode == 0) ? Qr : Kr;
        #pragma unroll
        for (int ni = 0; ni < NI; ++ni) {
            int c = col0 + wc * (TN / WC) + ni * 16 + lrow;
            int h = c >> 6, d = c & 63, pr = d >> 1;
            float bi = bias[c];
            #pragma unroll
            for (int mi = 0; mi < MI; ++mi) {
                int R0 = row0 + wr * (TM / WR) + mi * 16 + quad * 4;
                int bb = R0 >> 11;
                int n0 = R0 & 2047;
                float4 sv4 = *(const float4*)&st[pr * 2048 + n0];
                float4 cv4 = *(const float4*)&ct[pr * 2048 + n0];
                float svv[4] = {sv4.x, sv4.y, sv4.z, sv4.w};
                float cvv[4] = {cv4.x, cv4.y, cv4.z, cv4.w};
                #pragma unroll
                for (int reg = 0; reg < 4; ++reg) {
                    float x = acc[mi][ni][reg] + bi;
                    float p2 = __shfl_xor(x, 1, 64);       // partner column c^1
                    float y = (c & 1) ? fmaf(x, cvv[reg],  p2 * svv[reg])
                                      : fmaf(x, cvv[reg], -p2 * svv[reg]);
                    dst[(((size_t)(bb * Hc + h)) * Nc + n0 + reg) * Dc + d] = y;
                }
            }
        }
    } else if (mode == 2) {
        #pragma unroll
        for (int ni = 0; ni < NI; ++ni) {
            int c = col0 + wc * (TN / WC) + ni * 16 + lrow;
            int h = c >> 6, d = c & 63;
            float bi = bias[c];
            #pragma unroll
            for (int mi = 0; mi < MI; ++mi) {
                int R0 = row0 + wr * (TM / WR) + mi * 16 + quad * 4;
                int bb = R0 >> 11;
                int n0 = R0 & 2047;
                #pragma unroll
                for (int reg = 0; reg < 4; ++reg)
                    Vr[(((size_t)(bb * Hc + h)) * Nc + n0 + reg) * Dc + d] =
                        acc[mi][ni][reg] + bi;
            }
        }
    } else {
        #pragma unroll
        for (int ni = 0; ni < NI; ++ni) {
            int c = col0 + wc * (TN / WC) + ni * 16 + lrow;
            float bi = bias[c];
            #pragma unroll
            for (int mi = 0; mi < MI; ++mi) {
                int R0 = row0 + wr * (TM / WR) + mi * 16 + quad * 4;
                #pragma unroll
                for (int reg = 0; reg < 4; ++reg) {
                    float x = acc[mi][ni][reg] + bi;
                    if (mode == 3)
                        G[(size_t)(R0 + reg) * Ec + c] = x / (1.0f + expf(-x));
                    else
                        Out[(size_t)(R0 + reg) * Ec + c] = x;
                }
            }
        }
    }
}

// ---------------------------------------------------------------------------
// fp16 MFMA GEMM (single-term): 2-barrier double-buffered loop, counted
// VMCNT, global_load_lds staging, XOR-swizzled LDS, XCD-chunked swizzle.
// This is the m97/m103-verified configuration (912 TF @ 128^2 single dtype).
// C[r][c] = sum_k X[r][k]*W[c][k] + bias[c].
// mode: 0=Q (xpos*scale), 1=K (xpos/scale/8 folded), 2=V, 3=G (silu), 4=final
template<int TM, int TN, int WR, int WC>
__global__ __launch_bounds__(WR * WC * 64) void mgemm_kernel(
    const unsigned short* __restrict__ Xq, const unsigned short* __restrict__ Xk,
    const unsigned short* __restrict__ Xv, const unsigned short* __restrict__ Xr,
    const unsigned short* __restrict__ Wq, const unsigned short* __restrict__ Wk,
    const unsigned short* __restrict__ Wv, const unsigned short* __restrict__ Wg,
    const unsigned short* __restrict__ Wo,
    const float* __restrict__ bq, const float* __restrict__ bk, const float* __restrict__ bv,
    const float* __restrict__ bg, const float* __restrict__ bo,
    float* __restrict__ Qr, float* __restrict__ Kr, float* __restrict__ Vr,
    float* __restrict__ G, float* __restrict__ Out,
    const float* __restrict__ sinS, const float* __restrict__ cosS,
    const float* __restrict__ sinIS, const float* __restrict__ cosIS,
    int mode_base)
{
    constexpr int THREADS = WR * WC * 64;
    constexpr int MI  = TM / WR / 16;
    constexpr int NI  = TN / WC / 16;
    constexpr int RA  = TM * 4 / THREADS;      // A stage rounds (16B slots)
    constexpr int RB  = TN * 4 / THREADS;      // B stage rounds
    constexpr int GL  = RA + RB;               // GLOADs per thread per stage
    constexpr int BUF = (TM + TN) * 32;        // halves per K-step buffer
    constexpr int BHo = TM * 32;               // B offset (halves)
    static_assert(GL == 3 || GL == 4, "vmcnt literal");

    // XCD-chunked bijective swizzle (nwg % 8 == 0)
    int gx = gridDim.x, gy = gridDim.y;
    int nwg = gx * gy * gridDim.z;
    int id = blockIdx.x + gx * (blockIdx.y + gy * blockIdx.z);
    int sid = (id & 7) * (nwg >> 3) + (id >> 3);
    int bx = sid % gx; int rest = sid / gx;
    int by = rest % gy; int bz = rest / gy;

    int mode = mode_base + bz;
    const unsigned short *Xh, *Wh; const float* bias;
    switch (mode) {
        case 0:  Xh = Xq; Wh = Wq; bias = bq; break;
        case 1:  Xh = Xk; Wh = Wk; bias = bk; break;
        case 2:  Xh = Xv; Wh = Wv; bias = bv; break;
        case 3:  Xh = Xq; Wh = Wg; bias = bg; break;
        default: Xh = Xr; Wh = Wo; bias = bo; break;
    }

    __shared__ __align__(16) unsigned short lds[2 * BUF];

    int tid  = threadIdx.x;
    int lane = tid & 63;
    int w    = tid >> 6;
    int wr   = w / WC, wc = w % WC;
    int row0 = bx * TM, col0 = by * TN;
    int lrow = lane & 15, lslot = lane >> 4;

    f32x4 acc[MI][NI];
    #pragma unroll
    for (int i = 0; i < MI; ++i)
        #pragma unroll
        for (int j = 0; j < NI; ++j) acc[i][j] = {0.f, 0.f, 0.f, 0.f};

    int aoff[MI], boff[NI];
    #pragma unroll
    for (int mi = 0; mi < MI; ++mi) {
        int r = wr * (TM / WR) + mi * 16 + lrow;
        aoff[mi] = (r * 4 + (lslot ^ ((r >> 1) & 3))) * 8;
    }
    #pragma unroll
    for (int ni = 0; ni < NI; ++ni) {
        int r = wc * (TN / WC) + ni * 16 + lrow;
        boff[ni] = (r * 4 + (lslot ^ ((r >> 1) & 3))) * 8;
    }

    // stage one K-step tile (A then B), slot-linear dest, pre-swizzled source
    auto stage = [&](int buf, int k0) {
        unsigned short* l = &lds[buf * BUF];
        #pragma unroll
        for (int i = 0; i < RA; ++i) {
            int q = i * THREADS + tid;
            int r = q >> 2;
            int sp = (q & 3) ^ ((r >> 1) & 3);
            int base = (i * THREADS + (w << 6)) * 8;
            size_t ga = (size_t)(row0 + r) * Ec + k0 + sp * 8;
            GLOAD(Xh + ga, &l[base]);
        }
        #pragma unroll
        for (int i = 0; i < RB; ++i) {
            int q = i * THREADS + tid;
            int r = q >> 2;
            int sp = (q & 3) ^ ((r >> 1) & 3);
            int base = (i * THREADS + (w << 6)) * 8;
            size_t gb = (size_t)(col0 + r) * Ec + k0 + sp * 8;
            GLOAD(Wh + gb, &l[BHo + base]);
        }
    };

    stage(0, 0);
    for (int t = 0; t < Ec / 32; ++t) {
        int cur = t & 1;
        if (t < Ec / 32 - 1) {
            stage(cur ^ 1, (t + 1) * 32);
            // wait tile-t loads only; just-issued prefetch stays in flight
            if constexpr (GL == 4) VMCNT(4); else VMCNT(3);
        } else {
            VMCNT(0);
        }
        __builtin_amdgcn_s_barrier();
        __builtin_amdgcn_sched_barrier(0);

        const unsigned short* l = &lds[cur * BUF];
        f16x8 ah[MI], bh[NI];
        #pragma unroll
        for (int mi = 0; mi < MI; ++mi)
            ah[mi] = *(const f16x8*)&l[aoff[mi]];
        #pragma unroll
        for (int ni = 0; ni < NI; ++ni)
            bh[ni] = *(const f16x8*)&l[BHo + boff[ni]];
        #pragma unroll
        for (int mi = 0; mi < MI; ++mi)
            #pragma unroll
            for (int ni = 0; ni < NI; ++ni)
                acc[mi][ni] = __builtin_amdgcn_mfma_f32_16x16x32_f16(ah[mi], bh[ni], acc[mi][ni], 0, 0, 0);
        asm volatile("s_waitcnt lgkmcnt(0)" ::: "memory");
        __builtin_amdgcn_sched_barrier(0);
        __builtin_amdgcn_s_barrier();
    }

    gemm_epilogue<TM, TN, WR, WC, MI, NI>(acc, mode, row0, col0, wr, wc,
        lrow, lslot, bias, Qr, Kr, Vr, G, Out, (unsigned short*)nullptr,
        sinS, cosS, sinIS, cosIS);
}

// ---------------------------------------------------------------------------
// Phase A: per (bh, chunk) local state  L[dk][dv] = sum_s gamma^(64-s) K[s][dk] V[s][dv]
__global__ __launch_bounds__(256) void phaseA_kernel(const float* __restrict__ Kr,
                                                     const float* __restrict__ Vr,
                                                     float* __restrict__ L)
{
    int bh = blockIdx.x;
    int t  = blockIdx.y;
    float gamma = get_gamma(bh & 7);
    float lg = logf(gamma);

    __shared__ float Ks[64][68];
    __shared__ float Vs[64][68];

    int tid = threadIdx.x;
    const float* Kc = Kr + (size_t)(bh * Nc + t * Cc) * Dc;
    const float* Vc = Vr + (size_t)(bh * Nc + t * Cc) * Dc;

    #pragma unroll
    for (int i = 0; i < 4; ++i) {
        int f = tid + i * 256;
        int s = f >> 4;
        int d = (f & 15) << 2;
        float w = expf(lg * (float)(Cc - s));
        float4 kv = *(const float4*)&Kc[s * Dc + d];
        float4 ks = {kv.x * w, kv.y * w, kv.z * w, kv.w * w};
        *(float4*)&Ks[s][d] = ks;
        float4 vv = *(const float4*)&Vc[s * Dc + d];
        *(float4*)&Vs[s][d] = vv;
    }
    __syncthreads();

    int tx = tid & 15, ty = tid >> 4;
    float acc[4][4];
    #pragma unroll
    for (int i = 0; i < 4; ++i)
        #pragma unroll
        for (int j = 0; j < 4; ++j) acc[i][j] = 0.0f;

    for (int s = 0; s < 64; ++s) {
        float4 a = *(const float4*)&Ks[s][ty * 4];
        float4 b = *(const float4*)&Vs[s][tx * 4];
        float av[4] = {a.x, a.y, a.z, a.w};
        float bv[4] = {b.x, b.y, b.z, b.w};
        #pragma unroll
        for (int i = 0; i < 4; ++i)
            #pragma unroll
            for (int j = 0; j < 4; ++j)
                acc[i][j] = fmaf(av[i], bv[j], acc[i][j]);
    }

    float* Lp = L + (size_t)(bh * NT + t) * 4096;
    #pragma unroll
    for (int i = 0; i < 4; ++i) {
        float4 o = {acc[i][0], acc[i][1], acc[i][2], acc[i][3]};
        *(float4*)&Lp[(ty * 4 + i) * 64 + tx * 4] = o;
    }
}

// ---------------------------------------------------------------------------
// Phase B: S_0 = 0 ; S_{t+1} = gamma^64 * S_t + L_t  (S_t written pre-fold)
// grid (16, 16), 64-thread blocks: each block owns one 256-float slice.
__global__ __launch_bounds__(64) void scan_kernel(const float* __restrict__ L,
                                                  float* __restrict__ Sst)
{
    int bh = blockIdx.x;
    int part = blockIdx.y;
    int tid = threadIdx.x;
    float gamma = get_gamma(bh & 7);
    float g64 = expf(logf(gamma) * 64.0f);

    float4 s = {0.0f, 0.0f, 0.0f, 0.0f};
    size_t base = (size_t)bh * NT * 4096 + part * 256 + tid * 4;
    const float* Lp = L + base;
    float* Sp = Sst + base;
    for (int t = 0; t < NT; ++t) {
        *(float4*)&Sp[(size_t)t * 4096] = s;
        float4 l = *(const float4*)&Lp[(size_t)t * 4096];
        s.x = s.x * g64 + l.x;
        s.y = s.y * g64 + l.y;
        s.z = s.z * g64 + l.z;
        s.w = s.w * g64 + l.w;
    }
}

// ---------------------------------------------------------------------------
// Phase C: O = tril-decayed(QK^T) @ V + gamma^i * Q @ S, LayerNorm, gate,
// write retG as fp16 in (B,N,E) layout.
__global__ __launch_bounds__(256) void phaseC_kernel(
    const float* __restrict__ Qr, const float* __restrict__ Kr, const float* __restrict__ Vr,
    const float* __restrict__ Sst, const float* __restrict__ G,
    unsigned short* __restrict__ retG)
{
    int bh = blockIdx.x, t = blockIdx.y;
    int b = bh >> 3, h = bh & 7;
    float gamma = get_gamma(h);
    float lg = logf(gamma);

    __shared__ float QsT[64][68];
    __shared__ float KsT[64][68];
    __shared__ float Ss[64][68];

    int tid = threadIdx.x;
    const float* Qc = Qr + (size_t)(bh * Nc + t * Cc) * Dc;
    const float* Kc = Kr + (size_t)(bh * Nc + t * Cc) * Dc;
    const float* Sp = Sst + (size_t)(bh * NT + t) * 4096;

    #pragma unroll
    for (int i = 0; i < 4; ++i) {
        int f = tid + i * 256;
        int r = f >> 4;
        int d = (f & 15) << 2;
        float wq = expf(lg * (float)r);
        float4 q = *(const float4*)&Qc[r * Dc + d];
        QsT[d + 0][r] = q.x * wq; QsT[d + 1][r] = q.y * wq;
        QsT[d + 2][r] = q.z * wq; QsT[d + 3][r] = q.w * wq;
        float wk = expf(-lg * (float)r);
        float4 kk = *(const float4*)&Kc[r * Dc + d];
        KsT[d + 0][r] = kk.x * wk; KsT[d + 1][r] = kk.y * wk;
        KsT[d + 2][r] = kk.z * wk; KsT[d + 3][r] = kk.w * wk;
        float4 sv = *(const float4*)&Sp[r * 64 + d];
        *(float4*)&Ss[r][d] = sv;
    }
    __syncthreads();

    int tx = tid & 15, ty = tid >> 4;
    float accA[4][4], accO[4][4];
    #pragma unroll
    for (int i = 0; i < 4; ++i)
        #pragma unroll
        for (int j = 0; j < 4; ++j) { accA[i][j] = 0.0f; accO[i][j] = 0.0f; }

    for (int d = 0; d < 64; ++d) {
        float4 a  = *(const float4*)&QsT[d][ty * 4];
        float4 kb = *(const float4*)&KsT[d][tx * 4];
        float4 sb = *(const float4*)&Ss[d][tx * 4];
        float av[4] = {a.x, a.y, a.z, a.w};
        float kv[4] = {kb.x, kb.y, kb.z, kb.w};
        float sv[4] = {sb.x, sb.y, sb.z, sb.w};
        #pragma unroll
        for (int i = 0; i < 4; ++i)
            #pragma unroll
            for (int j = 0; j < 4; ++j) {
                accA[i][j] = fmaf(av[i], kv[j], accA[i][j]);
                accO[i][j] = fmaf(av[i], sv[j], accO[i][j]);
            }
    }
    __syncthreads();

    #pragma unroll
    for (int i = 0; i < 4; ++i) {
        int gi = ty * 4 + i;
        #pragma unroll
        for (int j = 0; j < 4; ++j) {
            int gj = tx * 4 + j;
            KsT[gj][gi] = (gj <= gi) ? accA[i][j] : 0.0f;
        }
    }
    const float* Vc = Vr + (size_t)(bh * Nc + t * Cc) * Dc;
    #pragma unroll
    for (int i = 0; i < 4; ++i) {
        int f = tid + i * 256;
        int r = f >> 4;
        int d = (f & 15) << 2;
        float4 vv = *(const float4*)&Vc[r * Dc + d];
        *(float4*)&QsT[r][d] = vv;
    }
    __syncthreads();

    for (int j = 0; j < 64; ++j) {
        float4 a = *(const float4*)&KsT[j][ty * 4];
        float4 v = *(const float4*)&QsT[j][tx * 4];
        float av[4] = {a.x, a.y, a.z, a.w};
        float vv[4] = {v.x, v.y, v.z, v.w};
        #pragma unroll
        for (int i = 0; i < 4; ++i)
            #pragma unroll
            for (int jj = 0; jj < 4; ++jj)
                accO[i][jj] = fmaf(av[i], vv[jj], accO[i][jj]);
    }

    // LayerNorm over D=64 per row (row spread across 16 tx lanes)
    #pragma unroll
    for (int i = 0; i < 4; ++i) {
        float sum = accO[i][0] + accO[i][1] + accO[i][2] + accO[i][3];
        float sq  = accO[i][0] * accO[i][0] + accO[i][1] * accO[i][1]
                  + accO[i][2] * accO[i][2] + accO[i][3] * accO[i][3];
        #pragma unroll
        for (int m = 1; m < 16; m <<= 1) {
            sum += __shfl_xor(sum, m, 64);
            sq  += __shfl_xor(sq,  m, 64);
        }
        float mean = sum * (1.0f / 64.0f);
        float var  = sq * (1.0f / 64.0f) - mean * mean;
        float rinv = rsqrtf(var + 1e-6f);
        #pragma unroll
        for (int jj = 0; jj < 4; ++jj)
            accO[i][jj] = (accO[i][jj] - mean) * rinv;
    }

    // gate multiply + fp16 store to (B, N, E)
    #pragma unroll
    for (int i = 0; i < 4; ++i) {
        int n = t * Cc + ty * 4 + i;
        size_t idx = ((size_t)b * Nc + n) * Ec + h * Dc + tx * 4;
        float4 g = *(const float4*)&G[idx];
        H4 o;
        o.h[0] = (_Float16)(accO[i][0] * g.x);
        o.h[1] = (_Float16)(accO[i][1] * g.y);
        o.h[2] = (_Float16)(accO[i][2] * g.z);
        o.h[3] = (_Float16)(accO[i][3] * g.w);
        *(ushort4*)&retG[idx] = o.u;
    }
}

// ---------------------------------------------------------------------------
extern "C" void kernel_launch(void* const* d_in, const int* in_sizes, int n_in,
                              void* d_out, int out_size, void* d_ws, size_t ws_size,
                              hipStream_t stream) {
    const float* query = (const float*)d_in[0];
    const float* key   = (const float*)d_in[1];
    const float* value = (const float*)d_in[2];
    const float* Wq = (const float*)d_in[3];
    const float* bq = (const float*)d_in[4];
    const float* Wk = (const float*)d_in[5];
    const float* bk = (const float*)d_in[6];
    const float* Wv = (const float*)d_in[7];
    const float* bv = (const float*)d_in[8];
    const float* Wg = (const float*)d_in[9];
    const float* bg = (const float*)d_in[10];
    const float* Wo = (const float*)d_in[11];
    const float* bo = (const float*)d_in[12];
    float* out = (float*)d_out;

    float* wsf = (float*)d_ws;
    const size_t SZ = (size_t)Bc * Nc * Ec;   // 2,097,152

    float* Qr = wsf;                 // fp32 (B,H,N,D)
    float* Kr = Qr + SZ;
    float* Vr = Kr + SZ;
    float* G  = Vr + SZ;             // fp32 (B,N,E)

    // fp16 arrays (SZ halves each = SZ/2 floats)
    unsigned short* Xq_f  = (unsigned short*)(wsf + 4 * SZ);
    unsigned short* Xk_f  = Xq_f + SZ;
    unsigned short* Xv_f  = Xk_f + SZ;
    unsigned short* retGf = Xv_f + SZ;          // [5.5SZ, 6SZ) floats

    float* L   = wsf + 6 * SZ;
    float* Sst = wsf + 7 * SZ;

    const size_t WSZ = (size_t)Ec * Ec;      // 262,144
    unsigned short* Wp = (unsigned short*)(wsf + 8 * SZ);
    unsigned short* Wq_f = Wp;
    unsigned short* Wk_f = Wp + WSZ;
    unsigned short* Wv_f = Wp + 2 * WSZ;
    unsigned short* Wg_f = Wp + 3 * WSZ;
    unsigned short* Wo_f = Wp + 4 * WSZ;

    float* tab = wsf + 8 * SZ + (5 * WSZ) / 2;
    float* sinS  = tab;
    float* cosS  = sinS + Nc * 32;
    float* sinIS = cosS + Nc * 32;
    float* cosIS = sinIS + Nc * 32;

    SplitArgs sa;
    sa.src[0] = query; sa.dst[0] = Xq_f; sa.n[0] = (int)SZ;
    sa.src[1] = key;   sa.dst[1] = Xk_f; sa.n[1] = (int)SZ;
    sa.src[2] = value; sa.dst[2] = Xv_f; sa.n[2] = (int)SZ;
    sa.src[3] = Wq;    sa.dst[3] = Wq_f; sa.n[3] = (int)WSZ;
    sa.src[4] = Wk;    sa.dst[4] = Wk_f; sa.n[4] = (int)WSZ;
    sa.src[5] = Wv;    sa.dst[5] = Wv_f; sa.n[5] = (int)WSZ;
    sa.src[6] = Wg;    sa.dst[6] = Wg_f; sa.n[6] = (int)WSZ;
    sa.src[7] = Wo;    sa.dst[7] = Wo_f; sa.n[7] = (int)WSZ;
    prep_kernel<<<dim3(2048, 9), dim3(256), 0, stream>>>(sa, sinS, cosS, sinIS, cosIS);

    // fused Q/K/V/G projections: 128x128, 2-barrier dbuf, fp16 single
    mgemm_kernel<128, 128, 2, 2><<<dim3(Mc / 128, Ec / 128, 4), dim3(256), 0, stream>>>(
        Xq_f, Xk_f, Xv_f, retGf,
        Wq_f, Wk_f, Wv_f, Wg_f, Wo_f,
        bq, bk, bv, bg, bo, Qr, Kr, Vr, G, out,
        sinS, cosS, sinIS, cosIS, 0);

    phaseA_kernel<<<dim3(Bc * Hc, NT), dim3(256), 0, stream>>>(Kr, Vr, L);
    scan_kernel<<<dim3(Bc * Hc, 16), dim3(64), 0, stream>>>(L, Sst);
    phaseC_kernel<<<dim3(Bc * Hc, NT), dim3(256), 0, stream>>>(Qr, Kr, Vr, Sst, G, retGf);

    // final: out = retG @ Wo^T + bo, 64x128, fp16 single (256 blocks)
    mgemm_kernel<64, 128, 2, 2><<<dim3(Mc / 64, Ec / 128, 1), dim3(256), 0, stream>>>(
        Xq_f, Xk_f, Xv_f, retGf,
        Wq_f, Wk_f, Wv_f, Wg_f, Wo_f,
        bq, bk, bv, bg, bo, Qr, Kr, Vr, G, out,
        sinS, cosS, sinIS, cosIS, 4);
}